// Round 1
// baseline (1208.379 us; speedup 1.0000x reference)
//
#include <hip/hip_runtime.h>
#include <hip/hip_bf16.h>
#include <math.h>
#include <stdint.h>

// Problem constants
#define E_DIM 1024
#define D_DIM 64
#define H_DIM 16
#define B_SZ  8
#define L_SEQ 4096
#define M_TOK (B_SZ * L_SEQ)   // 32768 tokens
#define NCAT  2112              // 1024 (a) + 1024 (b) + 64 (dx)
#define NPAD  2176              // padded to 17 tiles of 128
#define CHUNK 128               // scan chunk = GEMM M-tile
#define NCHUNK (L_SEQ / CHUNK)  // 32

typedef float  f32x4  __attribute__((ext_vector_type(4)));
typedef __bf16 bf16x8 __attribute__((ext_vector_type(8)));
typedef __bf16 bf16x4 __attribute__((ext_vector_type(4)));

__device__ __forceinline__ float wsum64(float v) {
#pragma unroll
  for (int off = 32; off > 0; off >>= 1) v += __shfl_xor(v, off, 64);
  return v;
}
__device__ __forceinline__ float bcast_lane(float v, int lane) {
  return __int_as_float(__builtin_amdgcn_readlane(__float_as_int(v), lane));
}
__device__ __forceinline__ float tanh_fast(float v) {
  float vc = fminf(fmaxf(v, -12.f), 12.f);
  float ex = __expf(vc + vc);
  return (ex - 1.f) / (ex + 1.f);
}
__device__ __forceinline__ void load_lds16(const void* g, void* l) {
  __builtin_amdgcn_global_load_lds(
      (const __attribute__((address_space(1))) void*)g,
      (__attribute__((address_space(3))) void*)l, 16, 0, 0);
}

// ---------------------------------------------------------------- cast emb f32 -> bf16
__global__ __launch_bounds__(256) void cast_emb(const float* __restrict__ in,
                                                bf16x4* __restrict__ out) {
  int i = blockIdx.x * 256 + threadIdx.x;      // exactly M_TOK*E/4 threads
  float4 v = ((const float4*)in)[i];
  bf16x4 o;
  o[0] = (__bf16)v.x; o[1] = (__bf16)v.y; o[2] = (__bf16)v.z; o[3] = (__bf16)v.w;
  out[i] = o;
}

// ---------------------------------------------------------------- pack Wa|Wb|Wd -> W^T [NPAD][E] bf16 + bias
__global__ __launch_bounds__(256) void pack_w(
    const float* __restrict__ Wa, const float* __restrict__ ba,
    const float* __restrict__ Wb, const float* __restrict__ bb,
    const float* __restrict__ Wd, const float* __restrict__ bd,
    __bf16* __restrict__ wcat, float* __restrict__ bias) {
  int gid = blockIdx.x * 256 + threadIdx.x;    // exactly NPAD*E threads
  int n = gid >> 10, k = gid & 1023;
  float w, bv;
  if (n < 1024) {        // a-gate: Wa[h,e,d], col n = h*64+d
    int h = n >> 6, d = n & 63;
    w = Wa[((h << 10) | k) * 64 + d]; bv = ba[n];
  } else if (n < 2048) { // b-gate
    int nn = n - 1024; int h = nn >> 6, d = nn & 63;
    w = Wb[((h << 10) | k) * 64 + d]; bv = bb[nn];
  } else if (n < NCAT) { // dx: Wd[e,d]
    int d = n - 2048;
    w = Wd[k * 64 + d];  bv = bd[d];
  } else { w = 0.f; bv = 0.f; }  // pad
  wcat[n * 1024 + k] = (__bf16)w;
  if (k == 0) bias[n] = bv;
}

// ---------------------------------------------------------------- bf16 MFMA GEMM, 128x128 tile, BK=64
// A [M,1024] bf16 row-major, Wt [NPAD,1024] bf16 (B^T).  Epilogue: +bias, tanh for a-cols.
__global__ __launch_bounds__(256) void gemm_fused(
    const __bf16* __restrict__ A, const __bf16* __restrict__ Wt,
    const float* __restrict__ bias,
    float* __restrict__ abuf, float* __restrict__ bbuf, float* __restrict__ dxbuf) {
  __shared__ __bf16 As[128 * 64];
  __shared__ __bf16 Bs[128 * 64];
  const int nt = blockIdx.x, mt = blockIdx.y;
  const int m0 = mt * 128, n0 = nt * 128;
  const int t = threadIdx.x, w = t >> 6, l = t & 63;
  const int lr = l >> 3, lc = l & 7;
  const int swz = lc ^ lr;            // XOR swizzle applied on the GLOBAL chunk index
  const int q = l >> 4, c16 = l & 15;

  f32x4 acc[4][4];
#pragma unroll
  for (int i = 0; i < 4; ++i)
#pragma unroll
    for (int j = 0; j < 4; ++j) acc[i][j] = (f32x4)(0.f);

  // per-lane global base addresses (row = w*8 + lr within each 32-row round)
  const __bf16* gA = A  + (size_t)(m0 + w * 8 + lr) * 1024 + swz * 8;
  const __bf16* gB = Wt + (size_t)(n0 + w * 8 + lr) * 1024 + swz * 8;
  __bf16* lA = As + w * 512;   // wave-uniform LDS base (+ r*2048 per round)
  __bf16* lB = Bs + w * 512;

  for (int kk = 0; kk < 16; ++kk) {
    const int k0 = kk * 64;
#pragma unroll
    for (int r = 0; r < 4; ++r) {
      load_lds16(gA + (size_t)r * 32 * 1024 + k0, lA + r * 2048);
      load_lds16(gB + (size_t)r * 32 * 1024 + k0, lB + r * 2048);
    }
    __syncthreads();
#pragma unroll
    for (int ks = 0; ks < 2; ++ks) {
      bf16x8 af[4], bfr[4];
#pragma unroll
      for (int i = 0; i < 4; ++i) {
        int mloc = (w >> 1) * 64 + i * 16 + c16;
        int cp = (ks * 4 + q) ^ (mloc & 7);
        af[i] = *(const bf16x8*)(As + mloc * 64 + cp * 8);
      }
#pragma unroll
      for (int j = 0; j < 4; ++j) {
        int nloc = (w & 1) * 64 + j * 16 + c16;
        int cp = (ks * 4 + q) ^ (nloc & 7);
        bfr[j] = *(const bf16x8*)(Bs + nloc * 64 + cp * 8);
      }
#pragma unroll
      for (int i = 0; i < 4; ++i)
#pragma unroll
        for (int j = 0; j < 4; ++j)
          acc[i][j] = __builtin_amdgcn_mfma_f32_16x16x32_bf16(af[i], bfr[j], acc[i][j], 0, 0, 0);
    }
    __syncthreads();
  }

  // epilogue: C/D layout col=lane&15 (N), row=(lane>>4)*4+reg (M)
#pragma unroll
  for (int j = 0; j < 4; ++j) {
    int n = n0 + (w & 1) * 64 + j * 16 + c16;
    float bv = bias[n];
#pragma unroll
    for (int i = 0; i < 4; ++i) {
      int mbase = m0 + (w >> 1) * 64 + i * 16 + q * 4;
#pragma unroll
      for (int r = 0; r < 4; ++r) {
        float v = acc[i][j][r] + bv;
        int m = mbase + r;
        if (n < 1024)            abuf[(size_t)m * 1024 + n] = tanh_fast(v);
        else if (n < 2048)       bbuf[(size_t)m * 1024 + (n - 1024)] = v;
        else if (n < NCAT)       dxbuf[m * 64 + (n - 2048)] = v;
        // n >= NCAT: pad, drop
      }
    }
  }
}

// ---------------------------------------------------------------- scan phase 1: chunk-local
// in-place: abuf <- cumprod(a) within chunk, bbuf <- local h (h0=0); per-chunk A,hlast out.
__global__ __launch_bounds__(256) void scan_local(
    float* __restrict__ abuf, float* __restrict__ bbuf,
    float* __restrict__ cA, float* __restrict__ cH) {
  int gid = blockIdx.x * 256 + threadIdx.x;    // 131072 threads, 2 columns each
  int n  = (gid & 511) << 1;
  int bc = gid >> 9;                            // global chunk id = m/128
  size_t base = (size_t)bc * CHUNK * 1024 + n;
  float2 p = {1.f, 1.f}, h = {0.f, 0.f};
  for (int s = 0; s < CHUNK; ++s) {
    size_t idx = base + (size_t)s * 1024;
    float2 av = *(const float2*)(abuf + idx);
    float2 bv = *(const float2*)(bbuf + idx);
    p.x *= av.x;                 p.y *= av.y;
    h.x = fmaf(av.x, h.x, bv.x); h.y = fmaf(av.y, h.y, bv.y);
    *(float2*)(abuf + idx) = p;
    *(float2*)(bbuf + idx) = h;
  }
  int ci = bc * 1024 + n;
  *(float2*)(cA + ci) = p;
  *(float2*)(cH + ci) = h;
}

// ---------------------------------------------------------------- scan phase 2: carries over chunks
__global__ __launch_bounds__(256) void scan_carry(
    const float* __restrict__ cA, const float* __restrict__ cH, float* __restrict__ cIn) {
  int gid = blockIdx.x * 256 + threadIdx.x;    // 8192 threads: (b, n)
  int n = gid & 1023, b = gid >> 10;
  float carry = 0.f;
  for (int c = 0; c < NCHUNK; ++c) {
    int idx = (b * NCHUNK + c) * 1024 + n;
    cIn[idx] = carry;                           // exclusive carry into chunk c
    carry = fmaf(cA[idx], carry, cH[idx]);
  }
}

// ---------------------------------------------------------------- heads: hs*Wc + bc + dx -> per-head LN -> weighted sum -> z -> u
__global__ __launch_bounds__(1024) void heads_kernel(
    const float* __restrict__ abuf, const float* __restrict__ bbuf,
    const float* __restrict__ dxbuf, const float* __restrict__ cIn,
    const float* __restrict__ Wc, const float* __restrict__ bch,
    const float* __restrict__ head_w, const float* __restrict__ hng,
    const float* __restrict__ hnb, const float* __restrict__ ng,
    const float* __restrict__ nbv, float* __restrict__ ubuf) {
  __shared__ float WcS[4 * 64 * 64];            // 64 KB: 4 heads at a time
  int wave = threadIdx.x >> 6, e = threadIdx.x & 63;
  int m = blockIdx.x * 16 + wave;               // one token per wave
  int b = m >> 12, lpos = m & 4095, c = lpos >> 7;
  size_t mb = (size_t)m * 1024;
  int cbase = (b * NCHUNK + c) * 1024;
  float dx_e = dxbuf[m * 64 + e];
  float accum = 0.f;

  for (int hp = 0; hp < 4; ++hp) {
    __syncthreads();
    for (int r = 0; r < 16; ++r) {              // stage 16384 floats with 1024 threads
      int idx = r * 1024 + threadIdx.x;
      WcS[idx] = Wc[hp * 16384 + idx];
    }
    __syncthreads();
#pragma unroll
    for (int hh = 0; hh < 4; ++hh) {
      int h = hp * 4 + hh;
      int nh = h * 64 + e;
      // reconstruct h_t = h_local + cumprod * carry_in  (reads a/b exactly once)
      float hreg = fmaf(abuf[mb + nh], cIn[cbase + nh], bbuf[mb + nh]);
      float val = bch[nh] + dx_e;
      const float* wcol = WcS + hh * 4096 + e;
#pragma unroll
      for (int d = 0; d < 64; ++d)
        val = fmaf(bcast_lane(hreg, d), wcol[d * 64], val);
      // per-head LayerNorm over e
      float s  = wsum64(val) * (1.f / 64.f);
      float s2 = wsum64(val * val) * (1.f / 64.f);
      float inv = rsqrtf(fmaxf(s2 - s * s, 0.f) + 1e-5f);
      float lnv = fmaf((val - s) * inv, hng[nh], hnb[nh]);
      accum = fmaf(head_w[h], lnv, accum);
    }
  }
  float z = (dx_e + accum) * (1.f / 16.f);
  float s  = wsum64(z) * (1.f / 64.f);
  float s2 = wsum64(z * z) * (1.f / 64.f);
  float inv = rsqrtf(fmaxf(s2 - s * s, 0.f) + 1e-5f);
  float u = z + fmaf((z - s) * inv, ng[e], nbv[e]);
  ubuf[m * 64 + e] = u;
}

// ---------------------------------------------------------------- FFN: gelu(u@W1+b1)@W2+b2, +u, @Wp+bp
__global__ __launch_bounds__(1024) void ffn_kernel(
    const float* __restrict__ ubuf, const float* __restrict__ W1,
    const float* __restrict__ b1, const float* __restrict__ W2,
    const float* __restrict__ b2, const float* __restrict__ Wp,
    const float* __restrict__ bp, float* __restrict__ out) {
  __shared__ __bf16 W1S[64 * 256];              // 32 KB
  __shared__ __bf16 W2S[256 * 64];              // 32 KB
  int tid = threadIdx.x;
  for (int r = 0; r < 16; ++r) {
    int idx = r * 1024 + tid;
    W1S[idx] = (__bf16)W1[idx];
    W2S[idx] = (__bf16)W2[idx];
  }
  __syncthreads();
  int wave = tid >> 6, e = tid & 63;
  int m = blockIdx.x * 16 + wave;
  float u = ubuf[m * 64 + e];
  float t1[4];
#pragma unroll
  for (int o = 0; o < 4; ++o) t1[o] = b1[o * 64 + e];
#pragma unroll
  for (int j = 0; j < 64; ++j) {
    float uj = bcast_lane(u, j);
#pragma unroll
    for (int o = 0; o < 4; ++o)
      t1[o] = fmaf(uj, (float)W1S[j * 256 + o * 64 + e], t1[o]);
  }
#pragma unroll
  for (int o = 0; o < 4; ++o) {
    float x = t1[o];
    t1[o] = 0.5f * x * (1.f + erff(x * 0.70710678118654752f));   // exact gelu
  }
  float f2 = b2[e];
#pragma unroll
  for (int j = 0; j < 256; ++j) {
    float tj = bcast_lane(t1[j >> 6], j & 63);
    f2 = fmaf(tj, (float)W2S[j * 64 + e], f2);
  }
  float hout = u + f2;
  float y = bp[e];
#pragma unroll
  for (int j = 0; j < 64; ++j) {
    float hj = bcast_lane(hout, j);
    y = fmaf(hj, Wp[j * 64 + e], y);            // Wp is 16 KB -> L1-resident
  }
  out[m * 64 + e] = y;
}

// ----------------------------------------------------------------
extern "C" void kernel_launch(void* const* d_in, const int* in_sizes, int n_in,
                              void* d_out, int out_size, void* d_ws, size_t ws_size,
                              hipStream_t stream) {
  const float* emb    = (const float*)d_in[0];
  const float* Wa     = (const float*)d_in[1];
  const float* ba     = (const float*)d_in[2];
  const float* Wb     = (const float*)d_in[3];
  const float* bb     = (const float*)d_in[4];
  const float* Wc     = (const float*)d_in[5];
  const float* bc     = (const float*)d_in[6];
  const float* head_w = (const float*)d_in[7];
  const float* hn_g   = (const float*)d_in[8];
  const float* hn_b   = (const float*)d_in[9];
  const float* Wd     = (const float*)d_in[10];
  const float* bd     = (const float*)d_in[11];
  const float* W1     = (const float*)d_in[12];
  const float* b1     = (const float*)d_in[13];
  const float* W2     = (const float*)d_in[14];
  const float* b2     = (const float*)d_in[15];
  const float* Wp     = (const float*)d_in[16];
  const float* bp     = (const float*)d_in[17];
  const float* ng     = (const float*)d_in[18];
  const float* nb     = (const float*)d_in[19];
  float* out = (float*)d_out;

  char* wsp = (char*)d_ws;
  size_t off = 0;
  auto alloc = [&](size_t bytes) -> char* {
    char* p = wsp + off;
    off += (bytes + 255) & ~(size_t)255;
    return p;
  };
  __bf16* embh  = (__bf16*)alloc((size_t)M_TOK * E_DIM * 2);   //  67 MB
  __bf16* wcat  = (__bf16*)alloc((size_t)NPAD * E_DIM * 2);    // 4.5 MB
  float*  bias  = (float*)alloc((size_t)NPAD * 4);
  float*  abuf  = (float*)alloc((size_t)M_TOK * 1024 * 4);     // 134 MB
  float*  bbuf  = (float*)alloc((size_t)M_TOK * 1024 * 4);     // 134 MB
  float*  dxbuf = (float*)alloc((size_t)M_TOK * 64 * 4);       // 8.4 MB
  float*  cA    = (float*)alloc((size_t)256 * 1024 * 4);
  float*  cH    = (float*)alloc((size_t)256 * 1024 * 4);
  float*  cIn   = (float*)alloc((size_t)256 * 1024 * 4);
  float*  ubuf  = (float*)alloc((size_t)M_TOK * 64 * 4);       // 8.4 MB

  cast_emb<<<dim3(32768), dim3(256), 0, stream>>>(emb, (bf16x4*)embh);
  pack_w<<<dim3(8704), dim3(256), 0, stream>>>(Wa, ba, Wb, bb, Wd, bd, wcat, bias);
  gemm_fused<<<dim3(17, 256), dim3(256), 0, stream>>>(embh, wcat, bias, abuf, bbuf, dxbuf);
  scan_local<<<dim3(512), dim3(256), 0, stream>>>(abuf, bbuf, cA, cH);
  scan_carry<<<dim3(32), dim3(256), 0, stream>>>(cA, cH, cIn);
  heads_kernel<<<dim3(2048), dim3(1024), 0, stream>>>(abuf, bbuf, dxbuf, cIn, Wc, bc,
                                                      head_w, hn_g, hn_b, ng, nb, ubuf);
  ffn_kernel<<<dim3(2048), dim3(1024), 0, stream>>>(ubuf, W1, b1, W2, b2, Wp, bp, out);
}

// Round 2
// 931.316 us; speedup vs baseline: 1.2975x; 1.2975x over previous
//
#include <hip/hip_runtime.h>
#include <hip/hip_bf16.h>
#include <math.h>
#include <stdint.h>

// Problem constants
#define E_DIM 1024
#define D_DIM 64
#define H_DIM 16
#define B_SZ  8
#define L_SEQ 4096
#define M_TOK (B_SZ * L_SEQ)   // 32768 tokens
#define NCAT  2112              // 1024 (a) + 1024 (b) + 64 (dx)
#define NPAD  2176              // padded to 17 tiles of 128
#define CHUNK 128               // scan chunk = GEMM M-tile
#define NCHUNK (L_SEQ / CHUNK)  // 32

typedef float  f32x4  __attribute__((ext_vector_type(4)));
typedef __bf16 bf16x8 __attribute__((ext_vector_type(8)));
typedef __bf16 bf16x4 __attribute__((ext_vector_type(4)));

__device__ __forceinline__ float wsum64(float v) {
#pragma unroll
  for (int off = 32; off > 0; off >>= 1) v += __shfl_xor(v, off, 64);
  return v;
}
__device__ __forceinline__ float bcast_lane(float v, int lane) {
  return __int_as_float(__builtin_amdgcn_readlane(__float_as_int(v), lane));
}
__device__ __forceinline__ float tanh_fast(float v) {
  float vc = fminf(fmaxf(v, -12.f), 12.f);
  float ex = __expf(vc + vc);
  return (ex - 1.f) / (ex + 1.f);
}
__device__ __forceinline__ void load_lds16(const void* g, void* l) {
  __builtin_amdgcn_global_load_lds(
      (const __attribute__((address_space(1))) void*)g,
      (__attribute__((address_space(3))) void*)l, 16, 0, 0);
}

// ---------------------------------------------------------------- cast emb f32 -> bf16
__global__ __launch_bounds__(256) void cast_emb(const float* __restrict__ in,
                                                bf16x4* __restrict__ out) {
  int i = blockIdx.x * 256 + threadIdx.x;      // exactly M_TOK*E/4 threads
  float4 v = ((const float4*)in)[i];
  bf16x4 o;
  o[0] = (__bf16)v.x; o[1] = (__bf16)v.y; o[2] = (__bf16)v.z; o[3] = (__bf16)v.w;
  out[i] = o;
}

// ---------------------------------------------------------------- pack Wa|Wb|Wd -> W^T [NPAD][E] bf16 + bias
__global__ __launch_bounds__(256) void pack_w(
    const float* __restrict__ Wa, const float* __restrict__ ba,
    const float* __restrict__ Wb, const float* __restrict__ bb,
    const float* __restrict__ Wd, const float* __restrict__ bd,
    __bf16* __restrict__ wcat, float* __restrict__ bias) {
  int gid = blockIdx.x * 256 + threadIdx.x;    // exactly NPAD*E threads
  int n = gid >> 10, k = gid & 1023;
  float w, bv;
  if (n < 1024) {        // a-gate: Wa[h,e,d], col n = h*64+d
    int h = n >> 6, d = n & 63;
    w = Wa[((h << 10) | k) * 64 + d]; bv = ba[n];
  } else if (n < 2048) { // b-gate
    int nn = n - 1024; int h = nn >> 6, d = nn & 63;
    w = Wb[((h << 10) | k) * 64 + d]; bv = bb[nn];
  } else if (n < NCAT) { // dx: Wd[e,d]
    int d = n - 2048;
    w = Wd[k * 64 + d];  bv = bd[d];
  } else { w = 0.f; bv = 0.f; }  // pad
  wcat[n * 1024 + k] = (__bf16)w;
  if (k == 0) bias[n] = bv;
}

// ---------------------------------------------------------------- pack FFN weights -> bf16 LDS-image layouts
// g_w1t: [256][72] bf16, g_w1t[n*72+k] = W1[k][n]           (36864 B)
// g_w2t: [64][256] bf16 chunk-swizzled: (n, k) at n*256 + ((k>>3)^(n&7))*8 + (k&7)  (32768 B)
// g_wpt: [64][72]  bf16, g_wpt[n*72+k] = Wp[k][n]           (9216 B)
__global__ __launch_bounds__(256) void pack_ffnw(
    const float* __restrict__ W1, const float* __restrict__ W2,
    const float* __restrict__ Wp,
    __bf16* __restrict__ g_w1t, __bf16* __restrict__ g_w2t,
    __bf16* __restrict__ g_wpt) {
  int idx = blockIdx.x * 256 + threadIdx.x;    // 36864 threads
  if (idx < 16384) {
    int k = idx >> 8, n = idx & 255;
    g_w1t[n * 72 + k] = (__bf16)W1[idx];
  } else if (idx < 32768) {
    int j = idx - 16384; int k = j >> 6, n = j & 63;
    g_w2t[n * 256 + (((k >> 3) ^ (n & 7)) << 3) + (k & 7)] = (__bf16)W2[j];
  } else {
    int j = idx - 32768; int k = j >> 6, n = j & 63;
    g_wpt[n * 72 + k] = (__bf16)Wp[j];
  }
}

// ---------------------------------------------------------------- bf16 MFMA GEMM, 128x128 tile, BK=64
// A [M,1024] bf16 row-major, Wt [NPAD,1024] bf16 (B^T).  Epilogue: +bias, tanh for a-cols.
__global__ __launch_bounds__(256) void gemm_fused(
    const __bf16* __restrict__ A, const __bf16* __restrict__ Wt,
    const float* __restrict__ bias,
    float* __restrict__ abuf, float* __restrict__ bbuf, float* __restrict__ dxbuf) {
  __shared__ __bf16 As[128 * 64];
  __shared__ __bf16 Bs[128 * 64];
  const int nt = blockIdx.x, mt = blockIdx.y;
  const int m0 = mt * 128, n0 = nt * 128;
  const int t = threadIdx.x, w = t >> 6, l = t & 63;
  const int lr = l >> 3, lc = l & 7;
  const int swz = lc ^ lr;            // XOR swizzle applied on the GLOBAL chunk index
  const int q = l >> 4, c16 = l & 15;

  f32x4 acc[4][4];
#pragma unroll
  for (int i = 0; i < 4; ++i)
#pragma unroll
    for (int j = 0; j < 4; ++j) acc[i][j] = (f32x4)(0.f);

  const __bf16* gA = A  + (size_t)(m0 + w * 8 + lr) * 1024 + swz * 8;
  const __bf16* gB = Wt + (size_t)(n0 + w * 8 + lr) * 1024 + swz * 8;
  __bf16* lA = As + w * 512;   // wave-uniform LDS base (+ r*2048 per round)
  __bf16* lB = Bs + w * 512;

  for (int kk = 0; kk < 16; ++kk) {
    const int k0 = kk * 64;
#pragma unroll
    for (int r = 0; r < 4; ++r) {
      load_lds16(gA + (size_t)r * 32 * 1024 + k0, lA + r * 2048);
      load_lds16(gB + (size_t)r * 32 * 1024 + k0, lB + r * 2048);
    }
    __syncthreads();
#pragma unroll
    for (int ks = 0; ks < 2; ++ks) {
      bf16x8 af[4], bfr[4];
#pragma unroll
      for (int i = 0; i < 4; ++i) {
        int mloc = (w >> 1) * 64 + i * 16 + c16;
        int cp = (ks * 4 + q) ^ (mloc & 7);
        af[i] = *(const bf16x8*)(As + mloc * 64 + cp * 8);
      }
#pragma unroll
      for (int j = 0; j < 4; ++j) {
        int nloc = (w & 1) * 64 + j * 16 + c16;
        int cp = (ks * 4 + q) ^ (nloc & 7);
        bfr[j] = *(const bf16x8*)(Bs + nloc * 64 + cp * 8);
      }
#pragma unroll
      for (int i = 0; i < 4; ++i)
#pragma unroll
        for (int j = 0; j < 4; ++j)
          acc[i][j] = __builtin_amdgcn_mfma_f32_16x16x32_bf16(af[i], bfr[j], acc[i][j], 0, 0, 0);
    }
    __syncthreads();
  }

  // epilogue: C/D layout col=lane&15 (N), row=(lane>>4)*4+reg (M)
#pragma unroll
  for (int j = 0; j < 4; ++j) {
    int n = n0 + (w & 1) * 64 + j * 16 + c16;
    float bv = bias[n];
#pragma unroll
    for (int i = 0; i < 4; ++i) {
      int mbase = m0 + (w >> 1) * 64 + i * 16 + q * 4;
#pragma unroll
      for (int r = 0; r < 4; ++r) {
        float v = acc[i][j][r] + bv;
        int m = mbase + r;
        if (n < 1024)            abuf[(size_t)m * 1024 + n] = tanh_fast(v);
        else if (n < 2048)       bbuf[(size_t)m * 1024 + (n - 1024)] = v;
        else if (n < NCAT)       dxbuf[m * 64 + (n - 2048)] = v;
      }
    }
  }
}

// ---------------------------------------------------------------- scan phase 1: chunk-local
__global__ __launch_bounds__(256) void scan_local(
    float* __restrict__ abuf, float* __restrict__ bbuf,
    float* __restrict__ cA, float* __restrict__ cH) {
  int gid = blockIdx.x * 256 + threadIdx.x;    // 131072 threads, 2 columns each
  int n  = (gid & 511) << 1;
  int bc = gid >> 9;                            // global chunk id = m/128
  size_t base = (size_t)bc * CHUNK * 1024 + n;
  float2 p = {1.f, 1.f}, h = {0.f, 0.f};
  for (int s = 0; s < CHUNK; ++s) {
    size_t idx = base + (size_t)s * 1024;
    float2 av = *(const float2*)(abuf + idx);
    float2 bv = *(const float2*)(bbuf + idx);
    p.x *= av.x;                 p.y *= av.y;
    h.x = fmaf(av.x, h.x, bv.x); h.y = fmaf(av.y, h.y, bv.y);
    *(float2*)(abuf + idx) = p;
    *(float2*)(bbuf + idx) = h;
  }
  int ci = bc * 1024 + n;
  *(float2*)(cA + ci) = p;
  *(float2*)(cH + ci) = h;
}

// ---------------------------------------------------------------- scan phase 2: carries over chunks
__global__ __launch_bounds__(256) void scan_carry(
    const float* __restrict__ cA, const float* __restrict__ cH, float* __restrict__ cIn) {
  int gid = blockIdx.x * 256 + threadIdx.x;    // 8192 threads: (b, n)
  int n = gid & 1023, b = gid >> 10;
  float carry = 0.f;
  for (int c = 0; c < NCHUNK; ++c) {
    int idx = (b * NCHUNK + c) * 1024 + n;
    cIn[idx] = carry;                           // exclusive carry into chunk c
    carry = fmaf(cA[idx], carry, cH[idx]);
  }
}

// ---------------------------------------------------------------- heads
__global__ __launch_bounds__(1024) void heads_kernel(
    const float* __restrict__ abuf, const float* __restrict__ bbuf,
    const float* __restrict__ dxbuf, const float* __restrict__ cIn,
    const float* __restrict__ Wc, const float* __restrict__ bch,
    const float* __restrict__ head_w, const float* __restrict__ hng,
    const float* __restrict__ hnb, const float* __restrict__ ng,
    const float* __restrict__ nbv, float* __restrict__ ubuf) {
  __shared__ float WcS[4 * 64 * 64];            // 64 KB: 4 heads at a time
  int wave = threadIdx.x >> 6, e = threadIdx.x & 63;
  int m = blockIdx.x * 16 + wave;               // one token per wave
  int b = m >> 12, lpos = m & 4095, c = lpos >> 7;
  size_t mb = (size_t)m * 1024;
  int cbase = (b * NCHUNK + c) * 1024;
  float dx_e = dxbuf[m * 64 + e];
  float accum = 0.f;

  for (int hp = 0; hp < 4; ++hp) {
    __syncthreads();
    for (int r = 0; r < 16; ++r) {
      int idx = r * 1024 + threadIdx.x;
      WcS[idx] = Wc[hp * 16384 + idx];
    }
    __syncthreads();
#pragma unroll
    for (int hh = 0; hh < 4; ++hh) {
      int h = hp * 4 + hh;
      int nh = h * 64 + e;
      float hreg = fmaf(abuf[mb + nh], cIn[cbase + nh], bbuf[mb + nh]);
      const float* wcol = WcS + hh * 4096 + e;
      // 4 independent accumulators: chain depth 16 instead of 64
      float p0 = 0.f, p1 = 0.f, p2 = 0.f, p3 = 0.f;
#pragma unroll
      for (int d = 0; d < 16; ++d) {
        p0 = fmaf(bcast_lane(hreg, d),      wcol[d * 64],        p0);
        p1 = fmaf(bcast_lane(hreg, d + 16), wcol[(d + 16) * 64], p1);
        p2 = fmaf(bcast_lane(hreg, d + 32), wcol[(d + 32) * 64], p2);
        p3 = fmaf(bcast_lane(hreg, d + 48), wcol[(d + 48) * 64], p3);
      }
      float val = bch[nh] + dx_e + ((p0 + p1) + (p2 + p3));
      float s  = wsum64(val) * (1.f / 64.f);
      float s2 = wsum64(val * val) * (1.f / 64.f);
      float inv = rsqrtf(fmaxf(s2 - s * s, 0.f) + 1e-5f);
      float lnv = fmaf((val - s) * inv, hng[nh], hnb[nh]);
      accum = fmaf(head_w[h], lnv, accum);
    }
  }
  float z = (dx_e + accum) * (1.f / 16.f);
  float s  = wsum64(z) * (1.f / 64.f);
  float s2 = wsum64(z * z) * (1.f / 64.f);
  float inv = rsqrtf(fmaxf(s2 - s * s, 0.f) + 1e-5f);
  float u = z + fmaf((z - s) * inv, ng[e], nbv[e]);
  ubuf[m * 64 + e] = u;
}

// ---------------------------------------------------------------- FFN via MFMA: 64-token tile, fused 3 GEMMs
// LDS pool (64 KB exactly), phases:
//   A: Us [64][72]@0, W1T [256][72]@4608        -> GEMM1 (K=64, N=256)
//   B: T1S [64][256]sw@0, W2T [64][256]sw@16384 -> GEMM2 (K=256, N=64) + residual
//   C: HoS [64][72]@0, WpT [64][72]@4608        -> GEMM3 (K=64, N=64)
__global__ __launch_bounds__(256) void ffn_mfma(
    const float* __restrict__ ubuf,
    const __bf16* __restrict__ g_w1t, const __bf16* __restrict__ g_w2t,
    const __bf16* __restrict__ g_wpt,
    const float* __restrict__ b1, const float* __restrict__ b2,
    const float* __restrict__ bp, float* __restrict__ out) {
  __shared__ __bf16 pool[32768];               // 65536 B
  const int tid = threadIdx.x, w = tid >> 6, l = tid & 63;
  const int q = l >> 4, c16 = l & 15;
  const int m0 = blockIdx.x * 64;
  __bf16* Us  = pool;            // stride 72
  __bf16* W1T = pool + 4608;     // stride 72
  __bf16* T1S = pool;            // stride 256, chunk-swizzled
  __bf16* W2T = pool + 16384;    // stride 256, chunk-swizzled
  __bf16* HoS = pool;            // stride 72
  __bf16* WpT = pool + 4608;     // stride 72

  // ---- phase A staging
#pragma unroll
  for (int r = 0; r < 16; ++r) {
    int idx = r * 256 + tid, m = idx >> 6, e = idx & 63;
    Us[m * 72 + e] = (__bf16)ubuf[(size_t)(m0 + m) * 64 + e];
  }
#pragma unroll
  for (int r = 0; r < 9; ++r)    // 2304 16B chunks = 36864 B
    load_lds16(g_w1t + (size_t)(r * 256 + tid) * 8,
               (char*)pool + 9216 + (r * 256 + w * 64) * 16);
  __syncthreads();

  // ---- GEMM1: t1[64x256] = u[64x64] @ W1
  f32x4 acc1[16];
#pragma unroll
  for (int j = 0; j < 16; ++j) acc1[j] = (f32x4)(0.f);
#pragma unroll
  for (int ks = 0; ks < 2; ++ks) {
    bf16x8 a = *(const bf16x8*)(Us + (w * 16 + c16) * 72 + ks * 32 + q * 8);
#pragma unroll
    for (int j = 0; j < 16; ++j) {
      bf16x8 b = *(const bf16x8*)(W1T + (j * 16 + c16) * 72 + ks * 32 + q * 8);
      acc1[j] = __builtin_amdgcn_mfma_f32_16x16x32_bf16(a, b, acc1[j], 0, 0, 0);
    }
  }
  __syncthreads();               // Us/W1T reads done before overwrite

  // ---- stage W2T + gelu -> T1S (bf16, swizzled)
#pragma unroll
  for (int r = 0; r < 8; ++r)    // 2048 chunks = 32768 B
    load_lds16(g_w2t + (size_t)(r * 256 + tid) * 8,
               (char*)pool + 32768 + (r * 256 + w * 64) * 16);
#pragma unroll
  for (int j = 0; j < 16; ++j) {
    int n = j * 16 + c16;
    float bv = b1[n];
#pragma unroll
    for (int rr = 0; rr < 4; ++rr) {
      int m = w * 16 + q * 4 + rr;
      float x = acc1[j][rr] + bv;
      float g = 0.5f * x * (1.f + erff(x * 0.70710678118654752f));
      T1S[m * 256 + (((n >> 3) ^ (m & 7)) << 3) + (n & 7)] = (__bf16)g;
    }
  }
  __syncthreads();

  // ---- GEMM2: f2[64x64] = t1 @ W2, + b2 + u residual (f32 from global)
  f32x4 acc2[4];
#pragma unroll
  for (int j = 0; j < 4; ++j) acc2[j] = (f32x4)(0.f);
  const int arow = w * 16 + c16;
#pragma unroll
  for (int ks = 0; ks < 8; ++ks) {
    bf16x8 a = *(const bf16x8*)(T1S + arow * 256 + (((ks * 4 + q) ^ (arow & 7)) << 3));
#pragma unroll
    for (int j = 0; j < 4; ++j) {
      int brow = j * 16 + c16;
      bf16x8 b = *(const bf16x8*)(W2T + brow * 256 + (((ks * 4 + q) ^ (brow & 7)) << 3));
      acc2[j] = __builtin_amdgcn_mfma_f32_16x16x32_bf16(a, b, acc2[j], 0, 0, 0);
    }
  }
  __syncthreads();               // T1S/W2T reads done before overwrite

  // ---- stage WpT + write HoS = u + f2 (bf16)
#pragma unroll
  for (int r = 0; r < 2; ++r)    // 512 of 576 chunks
    load_lds16(g_wpt + (size_t)(r * 256 + tid) * 8,
               (char*)pool + 9216 + (r * 256 + w * 64) * 16);
  if (tid < 64)                  // last 64 chunks, wave 0
    load_lds16(g_wpt + (size_t)(512 + tid) * 8, (char*)pool + 9216 + 512 * 16);
#pragma unroll
  for (int j = 0; j < 4; ++j) {
    int e = j * 16 + c16;
    float bv = b2[e];
#pragma unroll
    for (int rr = 0; rr < 4; ++rr) {
      int m = w * 16 + q * 4 + rr;
      float hres = acc2[j][rr] + bv + ubuf[(size_t)(m0 + m) * 64 + e];
      HoS[m * 72 + e] = (__bf16)hres;
    }
  }
  __syncthreads();

  // ---- GEMM3: out[64x64] = hout @ Wp + bp
  f32x4 acc3[4];
#pragma unroll
  for (int j = 0; j < 4; ++j) acc3[j] = (f32x4)(0.f);
#pragma unroll
  for (int ks = 0; ks < 2; ++ks) {
    bf16x8 a = *(const bf16x8*)(HoS + (w * 16 + c16) * 72 + ks * 32 + q * 8);
#pragma unroll
    for (int j = 0; j < 4; ++j) {
      bf16x8 b = *(const bf16x8*)(WpT + (j * 16 + c16) * 72 + ks * 32 + q * 8);
      acc3[j] = __builtin_amdgcn_mfma_f32_16x16x32_bf16(a, b, acc3[j], 0, 0, 0);
    }
  }
#pragma unroll
  for (int j = 0; j < 4; ++j) {
    int e = j * 16 + c16;
    float bv = bp[e];
#pragma unroll
    for (int rr = 0; rr < 4; ++rr) {
      int m = w * 16 + q * 4 + rr;
      out[(size_t)(m0 + m) * 64 + e] = acc3[j][rr] + bv;
    }
  }
}

// ----------------------------------------------------------------
extern "C" void kernel_launch(void* const* d_in, const int* in_sizes, int n_in,
                              void* d_out, int out_size, void* d_ws, size_t ws_size,
                              hipStream_t stream) {
  const float* emb    = (const float*)d_in[0];
  const float* Wa     = (const float*)d_in[1];
  const float* ba     = (const float*)d_in[2];
  const float* Wb     = (const float*)d_in[3];
  const float* bb     = (const float*)d_in[4];
  const float* Wc     = (const float*)d_in[5];
  const float* bc     = (const float*)d_in[6];
  const float* head_w = (const float*)d_in[7];
  const float* hn_g   = (const float*)d_in[8];
  const float* hn_b   = (const float*)d_in[9];
  const float* Wd     = (const float*)d_in[10];
  const float* bd     = (const float*)d_in[11];
  const float* W1     = (const float*)d_in[12];
  const float* b1     = (const float*)d_in[13];
  const float* W2     = (const float*)d_in[14];
  const float* b2     = (const float*)d_in[15];
  const float* Wp     = (const float*)d_in[16];
  const float* bp     = (const float*)d_in[17];
  const float* ng     = (const float*)d_in[18];
  const float* nb     = (const float*)d_in[19];
  float* out = (float*)d_out;

  char* wsp = (char*)d_ws;
  size_t off = 0;
  auto alloc = [&](size_t bytes) -> char* {
    char* p = wsp + off;
    off += (bytes + 255) & ~(size_t)255;
    return p;
  };
  __bf16* embh  = (__bf16*)alloc((size_t)M_TOK * E_DIM * 2);   //  67 MB
  __bf16* wcat  = (__bf16*)alloc((size_t)NPAD * E_DIM * 2);    // 4.5 MB
  float*  bias  = (float*)alloc((size_t)NPAD * 4);
  float*  abuf  = (float*)alloc((size_t)M_TOK * 1024 * 4);     // 134 MB
  float*  bbuf  = (float*)alloc((size_t)M_TOK * 1024 * 4);     // 134 MB
  float*  dxbuf = (float*)alloc((size_t)M_TOK * 64 * 4);       // 8.4 MB
  float*  cA    = (float*)alloc((size_t)256 * 1024 * 4);
  float*  cH    = (float*)alloc((size_t)256 * 1024 * 4);
  float*  cIn   = (float*)alloc((size_t)256 * 1024 * 4);
  float*  ubuf  = (float*)alloc((size_t)M_TOK * 64 * 4);       // 8.4 MB
  __bf16* g_w1t = (__bf16*)alloc((size_t)256 * 72 * 2);
  __bf16* g_w2t = (__bf16*)alloc((size_t)64 * 256 * 2);
  __bf16* g_wpt = (__bf16*)alloc((size_t)64 * 72 * 2);

  cast_emb<<<dim3(32768), dim3(256), 0, stream>>>(emb, (bf16x4*)embh);
  pack_w<<<dim3(8704), dim3(256), 0, stream>>>(Wa, ba, Wb, bb, Wd, bd, wcat, bias);
  pack_ffnw<<<dim3(144), dim3(256), 0, stream>>>(W1, W2, Wp, g_w1t, g_w2t, g_wpt);
  gemm_fused<<<dim3(17, 256), dim3(256), 0, stream>>>(embh, wcat, bias, abuf, bbuf, dxbuf);
  scan_local<<<dim3(512), dim3(256), 0, stream>>>(abuf, bbuf, cA, cH);
  scan_carry<<<dim3(32), dim3(256), 0, stream>>>(cA, cH, cIn);
  heads_kernel<<<dim3(2048), dim3(1024), 0, stream>>>(abuf, bbuf, dxbuf, cIn, Wc, bc,
                                                      head_w, hn_g, hn_b, ng, nb, ubuf);
  ffn_mfma<<<dim3(512), dim3(256), 0, stream>>>(ubuf, g_w1t, g_w2t, g_wpt,
                                                b1, b2, bp, out);
}

// Round 3
// 596.290 us; speedup vs baseline: 2.0265x; 1.5619x over previous
//
#include <hip/hip_runtime.h>
#include <hip/hip_bf16.h>
#include <math.h>
#include <stdint.h>

// Problem constants
#define E_DIM 1024
#define D_DIM 64
#define H_DIM 16
#define B_SZ  8
#define L_SEQ 4096
#define M_TOK (B_SZ * L_SEQ)   // 32768 tokens
#define NCAT  2112              // 1024 (a) + 1024 (b) + 64 (dx)
#define NPAD  2176              // padded to 17 tiles of 128
#define CHUNK 128               // scan chunk = GEMM M-tile
#define NCHUNK (L_SEQ / CHUNK)  // 32

typedef float  f32x4  __attribute__((ext_vector_type(4)));
typedef __bf16 bf16x8 __attribute__((ext_vector_type(8)));
typedef __bf16 bf16x4 __attribute__((ext_vector_type(4)));

__device__ __forceinline__ float tanh_fast(float v) {
  float vc = fminf(fmaxf(v, -12.f), 12.f);
  float ex = __expf(vc + vc);
  return (ex - 1.f) / (ex + 1.f);
}
__device__ __forceinline__ void load_lds16(const void* g, void* l) {
  __builtin_amdgcn_global_load_lds(
      (const __attribute__((address_space(1))) void*)g,
      (__attribute__((address_space(3))) void*)l, 16, 0, 0);
}

// ---------------------------------------------------------------- cast emb f32 -> bf16
__global__ __launch_bounds__(256) void cast_emb(const float* __restrict__ in,
                                                bf16x4* __restrict__ out) {
  int i = blockIdx.x * 256 + threadIdx.x;      // exactly M_TOK*E/4 threads
  float4 v = ((const float4*)in)[i];
  bf16x4 o;
  o[0] = (__bf16)v.x; o[1] = (__bf16)v.y; o[2] = (__bf16)v.z; o[3] = (__bf16)v.w;
  out[i] = o;
}

// ---------------------------------------------------------------- pack Wa|Wb|Wd -> W^T [NPAD][E] bf16 + bias
__global__ __launch_bounds__(256) void pack_w(
    const float* __restrict__ Wa, const float* __restrict__ ba,
    const float* __restrict__ Wb, const float* __restrict__ bb,
    const float* __restrict__ Wd, const float* __restrict__ bd,
    __bf16* __restrict__ wcat, float* __restrict__ bias) {
  int gid = blockIdx.x * 256 + threadIdx.x;    // exactly NPAD*E threads
  int n = gid >> 10, k = gid & 1023;
  float w, bv;
  if (n < 1024) {        // a-gate: Wa[h,e,d], col n = h*64+d
    int h = n >> 6, d = n & 63;
    w = Wa[((h << 10) | k) * 64 + d]; bv = ba[n];
  } else if (n < 2048) { // b-gate
    int nn = n - 1024; int h = nn >> 6, d = nn & 63;
    w = Wb[((h << 10) | k) * 64 + d]; bv = bb[nn];
  } else if (n < NCAT) { // dx: Wd[e,d]
    int d = n - 2048;
    w = Wd[k * 64 + d];  bv = bd[d];
  } else { w = 0.f; bv = 0.f; }  // pad
  wcat[n * 1024 + k] = (__bf16)w;
  if (k == 0) bias[n] = bv;
}

// ---------------------------------------------------------------- pack FFN weights -> bf16 LDS-image layouts
__global__ __launch_bounds__(256) void pack_ffnw(
    const float* __restrict__ W1, const float* __restrict__ W2,
    const float* __restrict__ Wp,
    __bf16* __restrict__ g_w1t, __bf16* __restrict__ g_w2t,
    __bf16* __restrict__ g_wpt) {
  int idx = blockIdx.x * 256 + threadIdx.x;    // 36864 threads
  if (idx < 16384) {
    int k = idx >> 8, n = idx & 255;
    g_w1t[n * 72 + k] = (__bf16)W1[idx];
  } else if (idx < 32768) {
    int j = idx - 16384; int k = j >> 6, n = j & 63;
    g_w2t[n * 256 + (((k >> 3) ^ (n & 7)) << 3) + (k & 7)] = (__bf16)W2[j];
  } else {
    int j = idx - 32768; int k = j >> 6, n = j & 63;
    g_wpt[n * 72 + k] = (__bf16)Wp[j];
  }
}

// ---------------------------------------------------------------- pack Wc -> WcT[h][e][d] bf16 (B^T layout for MFMA)
__global__ __launch_bounds__(256) void pack_wct(const float* __restrict__ Wc,
                                                __bf16* __restrict__ wct) {
  int idx = blockIdx.x * 256 + threadIdx.x;    // 65536 threads
  int h = idx >> 12, e = (idx >> 6) & 63, d = idx & 63;
  wct[idx] = (__bf16)Wc[h * 4096 + d * 64 + e];
}

// ---------------------------------------------------------------- bf16 MFMA GEMM, 128x128 tile, BK=64
// Epilogue: +bias, tanh for a-cols; a/b stored bf16, dx stored f32.
__global__ __launch_bounds__(256) void gemm_fused(
    const __bf16* __restrict__ A, const __bf16* __restrict__ Wt,
    const float* __restrict__ bias,
    __bf16* __restrict__ abuf, __bf16* __restrict__ bbuf, float* __restrict__ dxbuf) {
  __shared__ __bf16 As[128 * 64];
  __shared__ __bf16 Bs[128 * 64];
  const int nt = blockIdx.x, mt = blockIdx.y;
  const int m0 = mt * 128, n0 = nt * 128;
  const int t = threadIdx.x, w = t >> 6, l = t & 63;
  const int lr = l >> 3, lc = l & 7;
  const int swz = lc ^ lr;            // XOR swizzle applied on the GLOBAL chunk index
  const int q = l >> 4, c16 = l & 15;

  f32x4 acc[4][4];
#pragma unroll
  for (int i = 0; i < 4; ++i)
#pragma unroll
    for (int j = 0; j < 4; ++j) acc[i][j] = (f32x4)(0.f);

  const __bf16* gA = A  + (size_t)(m0 + w * 8 + lr) * 1024 + swz * 8;
  const __bf16* gB = Wt + (size_t)(n0 + w * 8 + lr) * 1024 + swz * 8;
  __bf16* lA = As + w * 512;   // wave-uniform LDS base (+ r*2048 per round)
  __bf16* lB = Bs + w * 512;

  for (int kk = 0; kk < 16; ++kk) {
    const int k0 = kk * 64;
#pragma unroll
    for (int r = 0; r < 4; ++r) {
      load_lds16(gA + (size_t)r * 32 * 1024 + k0, lA + r * 2048);
      load_lds16(gB + (size_t)r * 32 * 1024 + k0, lB + r * 2048);
    }
    __syncthreads();
#pragma unroll
    for (int ks = 0; ks < 2; ++ks) {
      bf16x8 af[4], bfr[4];
#pragma unroll
      for (int i = 0; i < 4; ++i) {
        int mloc = (w >> 1) * 64 + i * 16 + c16;
        int cp = (ks * 4 + q) ^ (mloc & 7);
        af[i] = *(const bf16x8*)(As + mloc * 64 + cp * 8);
      }
#pragma unroll
      for (int j = 0; j < 4; ++j) {
        int nloc = (w & 1) * 64 + j * 16 + c16;
        int cp = (ks * 4 + q) ^ (nloc & 7);
        bfr[j] = *(const bf16x8*)(Bs + nloc * 64 + cp * 8);
      }
#pragma unroll
      for (int i = 0; i < 4; ++i)
#pragma unroll
        for (int j = 0; j < 4; ++j)
          acc[i][j] = __builtin_amdgcn_mfma_f32_16x16x32_bf16(af[i], bfr[j], acc[i][j], 0, 0, 0);
    }
    __syncthreads();
  }

  // epilogue: C/D layout col=lane&15 (N), row=(lane>>4)*4+reg (M)
#pragma unroll
  for (int j = 0; j < 4; ++j) {
    int n = n0 + (w & 1) * 64 + j * 16 + c16;
    float bv = bias[n];
#pragma unroll
    for (int i = 0; i < 4; ++i) {
      int mbase = m0 + (w >> 1) * 64 + i * 16 + q * 4;
#pragma unroll
      for (int r = 0; r < 4; ++r) {
        float v = acc[i][j][r] + bv;
        int m = mbase + r;
        if (n < 1024)            abuf[(size_t)m * 1024 + n] = (__bf16)tanh_fast(v);
        else if (n < 2048)       bbuf[(size_t)m * 1024 + (n - 1024)] = (__bf16)v;
        else if (n < NCAT)       dxbuf[m * 64 + (n - 2048)] = v;
      }
    }
  }
}

// ---------------------------------------------------------------- scan phase 1: chunk-local, bf16 I/O, f32 math
// in-place: abuf <- cumprod(a), bbuf <- local h; per-chunk A,hlast out (f32).
__global__ __launch_bounds__(256) void scan_local_bf(
    __bf16* __restrict__ abuf, __bf16* __restrict__ bbuf,
    float* __restrict__ cA, float* __restrict__ cH) {
  int bc = blockIdx.x;                          // chunk id (m-major), 256 blocks
  int n4 = threadIdx.x * 4;                     // 4 columns per thread
  size_t base = (size_t)bc * CHUNK * 1024 + n4;
  float p[4] = {1.f, 1.f, 1.f, 1.f}, h[4] = {0.f, 0.f, 0.f, 0.f};
  for (int s = 0; s < CHUNK; ++s) {
    size_t idx = base + (size_t)s * 1024;
    bf16x4 av = *(const bf16x4*)(abuf + idx);
    bf16x4 bv = *(const bf16x4*)(bbuf + idx);
    bf16x4 po, ho;
#pragma unroll
    for (int i = 0; i < 4; ++i) {
      float a = (float)av[i];
      p[i] *= a;
      h[i] = fmaf(a, h[i], (float)bv[i]);
      po[i] = (__bf16)p[i];
      ho[i] = (__bf16)h[i];
    }
    *(bf16x4*)(abuf + idx) = po;
    *(bf16x4*)(bbuf + idx) = ho;
  }
  int ci = bc * 1024 + n4;                      // bc = b*32 + c (m-major) matches (b*NCHUNK+c)
  float4 pv = {p[0], p[1], p[2], p[3]};
  float4 hv = {h[0], h[1], h[2], h[3]};
  *(float4*)(cA + ci) = pv;
  *(float4*)(cH + ci) = hv;
}

// ---------------------------------------------------------------- scan phase 2: carries over chunks (f32)
__global__ __launch_bounds__(256) void scan_carry(
    const float* __restrict__ cA, const float* __restrict__ cH, float* __restrict__ cIn) {
  int gid = blockIdx.x * 256 + threadIdx.x;    // 8192 threads: (b, n)
  int n = gid & 1023, b = gid >> 10;
  float carry = 0.f;
  for (int c = 0; c < NCHUNK; ++c) {
    int idx = (b * NCHUNK + c) * 1024 + n;
    cIn[idx] = carry;                           // exclusive carry into chunk c
    carry = fmaf(cA[idx], carry, cH[idx]);
  }
}

// ---------------------------------------------------------------- heads via MFMA
// 64 tokens/block, 4 waves x 16 tokens each; all 16 heads per wave.
// out[t,h,e] = sum_d h[t,h,d]*Wc[h,d,e] + bc + dx -> per-head LN -> weighted sum -> z -> u
__global__ __launch_bounds__(256) void heads_mfma(
    const __bf16* __restrict__ ahat, const __bf16* __restrict__ hloc,
    const float* __restrict__ dxbuf, const float* __restrict__ cIn,
    const __bf16* __restrict__ wct, const float* __restrict__ bch,
    const float* __restrict__ head_w, const float* __restrict__ hng,
    const float* __restrict__ hnb, const float* __restrict__ ng,
    const float* __restrict__ nbv, float* __restrict__ ubuf) {
  __shared__ float carryS[1024];
  const int tid = threadIdx.x, w = tid >> 6, l = tid & 63;
  const int q = l >> 4, c16 = l & 15;
  const int m0 = blockIdx.x * 64;
  const int b = m0 >> 12, c = (m0 & 4095) >> 7;
  const int cb = (b * NCHUNK + c) * 1024;
  ((float4*)carryS)[tid] = ((const float4*)(cIn + cb))[tid];
  __syncthreads();

  const size_t arow = (size_t)(m0 + w * 16 + c16) * 1024;  // A-frag token row

  // dx regs in C layout: token q*4+r, e = j*16+c16
  float dxr[4][4];
#pragma unroll
  for (int j = 0; j < 4; ++j)
#pragma unroll
    for (int r = 0; r < 4; ++r)
      dxr[j][r] = dxbuf[(m0 + w * 16 + q * 4 + r) * 64 + j * 16 + c16];

  f32x4 accum[4];
#pragma unroll
  for (int j = 0; j < 4; ++j) accum[j] = (f32x4)(0.f);

  for (int h = 0; h < H_DIM; ++h) {
    // A fragments: reconstruct h_t = cumprod*carry + local (f32), cast bf16
    bf16x8 af[2];
#pragma unroll
    for (int ks = 0; ks < 2; ++ks) {
      int dbase = h * 64 + ks * 32 + q * 8;
      bf16x8 av = *(const bf16x8*)(ahat + arow + dbase);
      bf16x8 hv = *(const bf16x8*)(hloc + arow + dbase);
      float4 cv0 = *(const float4*)(carryS + dbase);
      float4 cv1 = *(const float4*)(carryS + dbase + 4);
      bf16x8 hf;
      hf[0] = (__bf16)fmaf((float)av[0], cv0.x, (float)hv[0]);
      hf[1] = (__bf16)fmaf((float)av[1], cv0.y, (float)hv[1]);
      hf[2] = (__bf16)fmaf((float)av[2], cv0.z, (float)hv[2]);
      hf[3] = (__bf16)fmaf((float)av[3], cv0.w, (float)hv[3]);
      hf[4] = (__bf16)fmaf((float)av[4], cv1.x, (float)hv[4]);
      hf[5] = (__bf16)fmaf((float)av[5], cv1.y, (float)hv[5]);
      hf[6] = (__bf16)fmaf((float)av[6], cv1.z, (float)hv[6]);
      hf[7] = (__bf16)fmaf((float)av[7], cv1.w, (float)hv[7]);
      af[ks] = hf;
    }
    // GEMM: [16 tokens x 64d] @ WcT[h] -> [16 x 64e]
    f32x4 acc[4];
#pragma unroll
    for (int j = 0; j < 4; ++j) acc[j] = (f32x4)(0.f);
#pragma unroll
    for (int ks = 0; ks < 2; ++ks)
#pragma unroll
      for (int j = 0; j < 4; ++j) {
        bf16x8 bf = *(const bf16x8*)(wct + h * 4096 + (j * 16 + c16) * 64 + ks * 32 + q * 8);
        acc[j] = __builtin_amdgcn_mfma_f32_16x16x32_bf16(af[ks], bf, acc[j], 0, 0, 0);
      }
    // bias + dx, per-head LN over e, weighted accumulate
    float hw = head_w[h];
    float g4[4], be4[4], bb4[4];
#pragma unroll
    for (int j = 0; j < 4; ++j) {
      int nh = h * 64 + j * 16 + c16;
      g4[j] = hng[nh]; bb4[j] = hnb[nh]; be4[j] = bch[nh];
    }
#pragma unroll
    for (int r = 0; r < 4; ++r) {
      float v0 = acc[0][r] + be4[0] + dxr[0][r];
      float v1 = acc[1][r] + be4[1] + dxr[1][r];
      float v2 = acc[2][r] + be4[2] + dxr[2][r];
      float v3 = acc[3][r] + be4[3] + dxr[3][r];
      float s  = (v0 + v1) + (v2 + v3);
      float s2 = fmaf(v0, v0, fmaf(v1, v1, fmaf(v2, v2, v3 * v3)));
#pragma unroll
      for (int off = 1; off < 16; off <<= 1) {
        s  += __shfl_xor(s, off, 64);
        s2 += __shfl_xor(s2, off, 64);
      }
      float mean = s * (1.f / 64.f);
      float var  = fmaf(s2, 1.f / 64.f, -mean * mean);
      float inv  = rsqrtf(fmaxf(var, 0.f) + 1e-5f);
      accum[0][r] = fmaf(hw, fmaf((v0 - mean) * inv, g4[0], bb4[0]), accum[0][r]);
      accum[1][r] = fmaf(hw, fmaf((v1 - mean) * inv, g4[1], bb4[1]), accum[1][r]);
      accum[2][r] = fmaf(hw, fmaf((v2 - mean) * inv, g4[2], bb4[2]), accum[2][r]);
      accum[3][r] = fmaf(hw, fmaf((v3 - mean) * inv, g4[3], bb4[3]), accum[3][r]);
    }
  }
  // z = (dx + accum)/16; u = z + LN(z)
  float ng4[4], nb4[4];
#pragma unroll
  for (int j = 0; j < 4; ++j) { ng4[j] = ng[j * 16 + c16]; nb4[j] = nbv[j * 16 + c16]; }
#pragma unroll
  for (int r = 0; r < 4; ++r) {
    float z0 = (dxr[0][r] + accum[0][r]) * (1.f / 16.f);
    float z1 = (dxr[1][r] + accum[1][r]) * (1.f / 16.f);
    float z2 = (dxr[2][r] + accum[2][r]) * (1.f / 16.f);
    float z3 = (dxr[3][r] + accum[3][r]) * (1.f / 16.f);
    float s  = (z0 + z1) + (z2 + z3);
    float s2 = fmaf(z0, z0, fmaf(z1, z1, fmaf(z2, z2, z3 * z3)));
#pragma unroll
    for (int off = 1; off < 16; off <<= 1) {
      s  += __shfl_xor(s, off, 64);
      s2 += __shfl_xor(s2, off, 64);
    }
    float mean = s * (1.f / 64.f);
    float var  = fmaf(s2, 1.f / 64.f, -mean * mean);
    float inv  = rsqrtf(fmaxf(var, 0.f) + 1e-5f);
    int mrow = (m0 + w * 16 + q * 4 + r) * 64;
    ubuf[mrow + 0 * 16 + c16] = z0 + fmaf((z0 - mean) * inv, ng4[0], nb4[0]);
    ubuf[mrow + 1 * 16 + c16] = z1 + fmaf((z1 - mean) * inv, ng4[1], nb4[1]);
    ubuf[mrow + 2 * 16 + c16] = z2 + fmaf((z2 - mean) * inv, ng4[2], nb4[2]);
    ubuf[mrow + 3 * 16 + c16] = z3 + fmaf((z3 - mean) * inv, ng4[3], nb4[3]);
  }
}

// ---------------------------------------------------------------- FFN via MFMA: 64-token tile, fused 3 GEMMs
__global__ __launch_bounds__(256) void ffn_mfma(
    const float* __restrict__ ubuf,
    const __bf16* __restrict__ g_w1t, const __bf16* __restrict__ g_w2t,
    const __bf16* __restrict__ g_wpt,
    const float* __restrict__ b1, const float* __restrict__ b2,
    const float* __restrict__ bp, float* __restrict__ out) {
  __shared__ __bf16 pool[32768];               // 65536 B
  const int tid = threadIdx.x, w = tid >> 6, l = tid & 63;
  const int q = l >> 4, c16 = l & 15;
  const int m0 = blockIdx.x * 64;
  __bf16* Us  = pool;            // stride 72
  __bf16* W1T = pool + 4608;     // stride 72
  __bf16* T1S = pool;            // stride 256, chunk-swizzled
  __bf16* W2T = pool + 16384;    // stride 256, chunk-swizzled
  __bf16* HoS = pool;            // stride 72
  __bf16* WpT = pool + 4608;     // stride 72

#pragma unroll
  for (int r = 0; r < 16; ++r) {
    int idx = r * 256 + tid, m = idx >> 6, e = idx & 63;
    Us[m * 72 + e] = (__bf16)ubuf[(size_t)(m0 + m) * 64 + e];
  }
#pragma unroll
  for (int r = 0; r < 9; ++r)    // 2304 16B chunks = 36864 B
    load_lds16(g_w1t + (size_t)(r * 256 + tid) * 8,
               (char*)pool + 9216 + (r * 256 + w * 64) * 16);
  __syncthreads();

  f32x4 acc1[16];
#pragma unroll
  for (int j = 0; j < 16; ++j) acc1[j] = (f32x4)(0.f);
#pragma unroll
  for (int ks = 0; ks < 2; ++ks) {
    bf16x8 a = *(const bf16x8*)(Us + (w * 16 + c16) * 72 + ks * 32 + q * 8);
#pragma unroll
    for (int j = 0; j < 16; ++j) {
      bf16x8 b = *(const bf16x8*)(W1T + (j * 16 + c16) * 72 + ks * 32 + q * 8);
      acc1[j] = __builtin_amdgcn_mfma_f32_16x16x32_bf16(a, b, acc1[j], 0, 0, 0);
    }
  }
  __syncthreads();

#pragma unroll
  for (int r = 0; r < 8; ++r)    // 2048 chunks = 32768 B
    load_lds16(g_w2t + (size_t)(r * 256 + tid) * 8,
               (char*)pool + 32768 + (r * 256 + w * 64) * 16);
#pragma unroll
  for (int j = 0; j < 16; ++j) {
    int n = j * 16 + c16;
    float bv = b1[n];
#pragma unroll
    for (int rr = 0; rr < 4; ++rr) {
      int m = w * 16 + q * 4 + rr;
      float x = acc1[j][rr] + bv;
      float g = 0.5f * x * (1.f + erff(x * 0.70710678118654752f));
      T1S[m * 256 + (((n >> 3) ^ (m & 7)) << 3) + (n & 7)] = (__bf16)g;
    }
  }
  __syncthreads();

  f32x4 acc2[4];
#pragma unroll
  for (int j = 0; j < 4; ++j) acc2[j] = (f32x4)(0.f);
  const int arow2 = w * 16 + c16;
#pragma unroll
  for (int ks = 0; ks < 8; ++ks) {
    bf16x8 a = *(const bf16x8*)(T1S + arow2 * 256 + (((ks * 4 + q) ^ (arow2 & 7)) << 3));
#pragma unroll
    for (int j = 0; j < 4; ++j) {
      int brow = j * 16 + c16;
      bf16x8 b = *(const bf16x8*)(W2T + brow * 256 + (((ks * 4 + q) ^ (brow & 7)) << 3));
      acc2[j] = __builtin_amdgcn_mfma_f32_16x16x32_bf16(a, b, acc2[j], 0, 0, 0);
    }
  }
  __syncthreads();

#pragma unroll
  for (int r = 0; r < 2; ++r)    // 512 of 576 chunks
    load_lds16(g_wpt + (size_t)(r * 256 + tid) * 8,
               (char*)pool + 9216 + (r * 256 + w * 64) * 16);
  if (tid < 64)                  // last 64 chunks, wave 0
    load_lds16(g_wpt + (size_t)(512 + tid) * 8, (char*)pool + 9216 + 512 * 16);
#pragma unroll
  for (int j = 0; j < 4; ++j) {
    int e = j * 16 + c16;
    float bv = b2[e];
#pragma unroll
    for (int rr = 0; rr < 4; ++rr) {
      int m = w * 16 + q * 4 + rr;
      float hres = acc2[j][rr] + bv + ubuf[(size_t)(m0 + m) * 64 + e];
      HoS[m * 72 + e] = (__bf16)hres;
    }
  }
  __syncthreads();

  f32x4 acc3[4];
#pragma unroll
  for (int j = 0; j < 4; ++j) acc3[j] = (f32x4)(0.f);
#pragma unroll
  for (int ks = 0; ks < 2; ++ks) {
    bf16x8 a = *(const bf16x8*)(HoS + (w * 16 + c16) * 72 + ks * 32 + q * 8);
#pragma unroll
    for (int j = 0; j < 4; ++j) {
      bf16x8 b = *(const bf16x8*)(WpT + (j * 16 + c16) * 72 + ks * 32 + q * 8);
      acc3[j] = __builtin_amdgcn_mfma_f32_16x16x32_bf16(a, b, acc3[j], 0, 0, 0);
    }
  }
#pragma unroll
  for (int j = 0; j < 4; ++j) {
    int e = j * 16 + c16;
    float bv = bp[e];
#pragma unroll
    for (int rr = 0; rr < 4; ++rr) {
      int m = w * 16 + q * 4 + rr;
      out[(size_t)(m0 + m) * 64 + e] = acc3[j][rr] + bv;
    }
  }
}

// ----------------------------------------------------------------
extern "C" void kernel_launch(void* const* d_in, const int* in_sizes, int n_in,
                              void* d_out, int out_size, void* d_ws, size_t ws_size,
                              hipStream_t stream) {
  const float* emb    = (const float*)d_in[0];
  const float* Wa     = (const float*)d_in[1];
  const float* ba     = (const float*)d_in[2];
  const float* Wb     = (const float*)d_in[3];
  const float* bb     = (const float*)d_in[4];
  const float* Wc     = (const float*)d_in[5];
  const float* bc     = (const float*)d_in[6];
  const float* head_w = (const float*)d_in[7];
  const float* hn_g   = (const float*)d_in[8];
  const float* hn_b   = (const float*)d_in[9];
  const float* Wd     = (const float*)d_in[10];
  const float* bd     = (const float*)d_in[11];
  const float* W1     = (const float*)d_in[12];
  const float* b1     = (const float*)d_in[13];
  const float* W2     = (const float*)d_in[14];
  const float* b2     = (const float*)d_in[15];
  const float* Wp     = (const float*)d_in[16];
  const float* bp     = (const float*)d_in[17];
  const float* ng     = (const float*)d_in[18];
  const float* nb     = (const float*)d_in[19];
  float* out = (float*)d_out;

  char* wsp = (char*)d_ws;
  size_t off = 0;
  auto alloc = [&](size_t bytes) -> char* {
    char* p = wsp + off;
    off += (bytes + 255) & ~(size_t)255;
    return p;
  };
  __bf16* embh  = (__bf16*)alloc((size_t)M_TOK * E_DIM * 2);   //  67 MB
  __bf16* wcat  = (__bf16*)alloc((size_t)NPAD * E_DIM * 2);    // 4.5 MB
  float*  bias  = (float*)alloc((size_t)NPAD * 4);
  __bf16* abuf  = (__bf16*)alloc((size_t)M_TOK * 1024 * 2);    // 67 MB
  __bf16* bbuf  = (__bf16*)alloc((size_t)M_TOK * 1024 * 2);    // 67 MB
  float*  dxbuf = (float*)alloc((size_t)M_TOK * 64 * 4);       // 8.4 MB
  float*  cA    = (float*)alloc((size_t)256 * 1024 * 4);
  float*  cH    = (float*)alloc((size_t)256 * 1024 * 4);
  float*  cIn   = (float*)alloc((size_t)256 * 1024 * 4);
  float*  ubuf  = (float*)alloc((size_t)M_TOK * 64 * 4);       // 8.4 MB
  __bf16* g_w1t = (__bf16*)alloc((size_t)256 * 72 * 2);
  __bf16* g_w2t = (__bf16*)alloc((size_t)64 * 256 * 2);
  __bf16* g_wpt = (__bf16*)alloc((size_t)64 * 72 * 2);
  __bf16* wct   = (__bf16*)alloc((size_t)H_DIM * 64 * 64 * 2); // 128 KB

  cast_emb<<<dim3(32768), dim3(256), 0, stream>>>(emb, (bf16x4*)embh);
  pack_w<<<dim3(8704), dim3(256), 0, stream>>>(Wa, ba, Wb, bb, Wd, bd, wcat, bias);
  pack_ffnw<<<dim3(144), dim3(256), 0, stream>>>(W1, W2, Wp, g_w1t, g_w2t, g_wpt);
  pack_wct<<<dim3(256), dim3(256), 0, stream>>>(Wc, wct);
  gemm_fused<<<dim3(17, 256), dim3(256), 0, stream>>>(embh, wcat, bias, abuf, bbuf, dxbuf);
  scan_local_bf<<<dim3(256), dim3(256), 0, stream>>>(abuf, bbuf, cA, cH);
  scan_carry<<<dim3(32), dim3(256), 0, stream>>>(cA, cH, cIn);
  heads_mfma<<<dim3(512), dim3(256), 0, stream>>>(abuf, bbuf, dxbuf, cIn, wct, bc,
                                                  head_w, hn_g, hn_b, ng, nb, ubuf);
  ffn_mfma<<<dim3(512), dim3(256), 0, stream>>>(ubuf, g_w1t, g_w2t, g_wpt,
                                                b1, b2, bp, out);
}